// Round 8
// baseline (291.277 us; speedup 1.0000x reference)
//
#include <hip/hip_runtime.h>

typedef __bf16 bfrag __attribute__((ext_vector_type(8)));
typedef __bf16 bh4 __attribute__((ext_vector_type(4)));
typedef float f4 __attribute__((ext_vector_type(4)));

#define AS1C(p) (const __attribute__((address_space(1))) void*)(p)
#define AS3(p)  (__attribute__((address_space(3))) void*)(p)

// 0.125 (=1/sqrt(64)) * log2(e): folded into Q so softmax is a bare exp2
#define QSCALE 0.18033688011112042f

__device__ __forceinline__ void g2l16(const __bf16* g, __bf16* l) {
  __builtin_amdgcn_global_load_lds(AS1C(g), AS3(l), 16, 0, 0);
}

// ---------- f32 -> bf16 bulk convert: x + 4 weights in one dispatch ----------
__global__ __launch_bounds__(256) void cvt5(
    const float* __restrict__ s0, const float* __restrict__ s1,
    const float* __restrict__ s2, const float* __restrict__ s3,
    const float* __restrict__ s4,
    __bf16* __restrict__ d0, __bf16* __restrict__ d1, __bf16* __restrict__ d2,
    __bf16* __restrict__ d3, __bf16* __restrict__ d4, long n0, long n1) {
  const float* s; __bf16* d; long n;
  switch (blockIdx.y) {
    case 0: s = s0; d = d0; n = n0; break;
    case 1: s = s1; d = d1; n = n1; break;
    case 2: s = s2; d = d2; n = n1; break;
    case 3: s = s3; d = d3; n = n1; break;
    default: s = s4; d = d4; n = n1; break;
  }
  long i = ((long)blockIdx.x * 256 + threadIdx.x) * 8;
  if (i >= n) return;
  float4 a = *(const float4*)(s + i);
  float4 b = *(const float4*)(s + i + 4);
  bfrag o;
  o[0] = (__bf16)a.x; o[1] = (__bf16)a.y; o[2] = (__bf16)a.z; o[3] = (__bf16)a.w;
  o[4] = (__bf16)b.x; o[5] = (__bf16)b.y; o[6] = (__bf16)b.z; o[7] = (__bf16)b.w;
  *(bfrag*)(d + i) = o;
}

// ---------- fused QKV GEMM, BK=64 (two BK-32 substages per barrier) ----------
// q (bn<1024): *QSCALE -> qb.  k: -> kb.  v: transposed+kappa' -> vt via LDS.
__global__ __launch_bounds__(256) void gemm_qkv(
    const __bf16* __restrict__ A, const __bf16* __restrict__ B,
    __bf16* __restrict__ qb, __bf16* __restrict__ kb, __bf16* __restrict__ vt,
    int M, int K) {
  __shared__ __bf16 sbuf[16640];  // k-loop: As0|As1|Bs0|Bs1 (4x4096); V-epi: 128x130
  __bf16* As0 = sbuf;
  __bf16* As1 = sbuf + 4096;
  __bf16* Bs0 = sbuf + 8192;
  __bf16* Bs1 = sbuf + 12288;
  const int tid = threadIdx.x;
  const int wave = tid >> 6, lane = tid & 63;
  const int lm = lane & 15, quad = lane >> 4;
  const int bm = blockIdx.x * 128, bn = blockIdx.y * 128;
  const int wr = (wave >> 1) * 64, wc = (wave & 1) * 64;
  f4 acc[4][4] = {};
  for (int k0 = 0; k0 < K; k0 += 64) {
#pragma unroll
    for (int ii = 0; ii < 2; ++ii) {
      int s = ii * 4 + wave;
      int e = s * 512 + lane * 8;
      int r = e >> 5, c = e & 31;
      const __bf16* ar = A + (long)(bm + r) * K + k0 + c;
      const __bf16* br = B + (long)(bn + r) * K + k0 + c;
      g2l16(ar, As0 + e);
      g2l16(ar + 32, As1 + e);
      g2l16(br, Bs0 + e);
      g2l16(br + 32, Bs1 + e);
    }
    __syncthreads();
#pragma unroll
    for (int st = 0; st < 2; ++st) {
      const __bf16* As = st ? As1 : As0;
      const __bf16* Bs = st ? Bs1 : Bs0;
      bfrag af[4], bg[4];
#pragma unroll
      for (int mi = 0; mi < 4; ++mi)
        af[mi] = *(const bfrag*)(As + (wr + mi * 16 + lm) * 32 + quad * 8);
#pragma unroll
      for (int ni = 0; ni < 4; ++ni)
        bg[ni] = *(const bfrag*)(Bs + (wc + ni * 16 + lm) * 32 + quad * 8);
#pragma unroll
      for (int mi = 0; mi < 4; ++mi)
#pragma unroll
        for (int ni = 0; ni < 4; ++ni)
          acc[mi][ni] = __builtin_amdgcn_mfma_f32_16x16x32_bf16(af[mi], bg[ni], acc[mi][ni], 0, 0, 0);
    }
    __syncthreads();
  }
  if (bn < 2048) {
    __bf16* dst = (bn < 1024) ? qb : kb;
    const float scl = (bn < 1024) ? QSCALE : 1.0f;
    const int nb = bn & 1023;
#pragma unroll
    for (int mi = 0; mi < 4; ++mi)
#pragma unroll
      for (int ni = 0; ni < 4; ++ni)
#pragma unroll
        for (int r = 0; r < 4; ++r) {
          long row = bm + wr + mi * 16 + quad * 4 + r;
          long col = nb + wc + ni * 16 + lm;
          dst[row * 1024 + col] = (__bf16)(acc[mi][ni][r] * scl);
        }
  } else {
    // V: acc(row=t, col=d) -> Tt[d][t'], t' = (t>>6)*64 + kappa'(t&63)
#pragma unroll
    for (int mi = 0; mi < 4; ++mi)
#pragma unroll
      for (int ni = 0; ni < 4; ++ni)
#pragma unroll
        for (int r = 0; r < 4; ++r) {
          int d = wc + ni * 16 + lm;
          int tp = (wr ? 64 : 0) + (quad * 4 + r) * 4 + mi;
          sbuf[d * 130 + tp] = (__bf16)acc[mi][ni][r];
        }
    __syncthreads();
    const int bloc = bm >> 11;
    const int tloc = bm & 2047;
#pragma unroll
    for (int p = 0; p < 8; ++p) {
      int d = (tid >> 4) + p * 16;
      int c = (tid & 15) * 8;
      long dglob = (bn - 2048) + d;
      *(bfrag*)(vt + ((long)bloc * 1024 + dglob) * 2048 + tloc + c) =
          *(const bfrag*)(sbuf + d * 130 + c);
    }
  }
}

// ---------- plain GEMM (bf16 in), BK=64, final projection ----------
template <bool OUT_F32>
__global__ __launch_bounds__(256) void gemm_bt_bf16(
    const __bf16* __restrict__ A, const __bf16* __restrict__ B,
    void* __restrict__ Cp, int M, int N, int K) {
  __shared__ __bf16 sbuf[16384];
  __bf16* As0 = sbuf;
  __bf16* As1 = sbuf + 4096;
  __bf16* Bs0 = sbuf + 8192;
  __bf16* Bs1 = sbuf + 12288;
  const int tid = threadIdx.x;
  const int wave = tid >> 6, lane = tid & 63;
  const int lm = lane & 15, quad = lane >> 4;
  const int bm = blockIdx.x * 128, bn = blockIdx.y * 128;
  const int wr = (wave >> 1) * 64, wc = (wave & 1) * 64;
  f4 acc[4][4] = {};
  for (int k0 = 0; k0 < K; k0 += 64) {
#pragma unroll
    for (int ii = 0; ii < 2; ++ii) {
      int s = ii * 4 + wave;
      int e = s * 512 + lane * 8;
      int r = e >> 5, c = e & 31;
      const __bf16* ar = A + (long)(bm + r) * K + k0 + c;
      const __bf16* br = B + (long)(bn + r) * K + k0 + c;
      g2l16(ar, As0 + e);
      g2l16(ar + 32, As1 + e);
      g2l16(br, Bs0 + e);
      g2l16(br + 32, Bs1 + e);
    }
    __syncthreads();
#pragma unroll
    for (int st = 0; st < 2; ++st) {
      const __bf16* As = st ? As1 : As0;
      const __bf16* Bs = st ? Bs1 : Bs0;
      bfrag af[4], bg[4];
#pragma unroll
      for (int mi = 0; mi < 4; ++mi)
        af[mi] = *(const bfrag*)(As + (wr + mi * 16 + lm) * 32 + quad * 8);
#pragma unroll
      for (int ni = 0; ni < 4; ++ni)
        bg[ni] = *(const bfrag*)(Bs + (wc + ni * 16 + lm) * 32 + quad * 8);
#pragma unroll
      for (int mi = 0; mi < 4; ++mi)
#pragma unroll
        for (int ni = 0; ni < 4; ++ni)
          acc[mi][ni] = __builtin_amdgcn_mfma_f32_16x16x32_bf16(af[mi], bg[ni], acc[mi][ni], 0, 0, 0);
    }
    __syncthreads();
  }
#pragma unroll
  for (int mi = 0; mi < 4; ++mi)
#pragma unroll
    for (int ni = 0; ni < 4; ++ni)
#pragma unroll
      for (int r = 0; r < 4; ++r) {
        long row = bm + wr + mi * 16 + quad * 4 + r;
        long col = bn + wc + ni * 16 + lm;
        if (OUT_F32) ((float*)Cp)[row * N + col] = acc[mi][ni][r];
        else ((__bf16*)Cp)[row * N + col] = (__bf16)acc[mi][ni][r];
      }
}

// ---------- fallback GEMM (f32 A / f32 B, inline convert) ----------
template <bool A_F32, bool OUT_F32>
__global__ __launch_bounds__(256) void gemm_bt_cv(
    const void* __restrict__ Ap, const float* __restrict__ Bp,
    void* __restrict__ Cp, int M, int N, int K, float scl) {
  __shared__ __bf16 As[128 * 32];
  __shared__ __bf16 Bs[128 * 32];
  const int tid = threadIdx.x;
  const int lane = tid & 63, wave = tid >> 6;
  const int lm = lane & 15, quad = lane >> 4;
  const int bm = blockIdx.x * 128, bn = blockIdx.y * 128;
  const int wr = (wave >> 1) * 64, wc = (wave & 1) * 64;
  const int e0 = tid * 16, sr = e0 >> 5, sc = e0 & 31;
  f4 acc[4][4] = {};
  for (int k0 = 0; k0 < K; k0 += 32) {
    if (A_F32) {
      const float4* ga = (const float4*)((const float*)Ap + (long)(bm + sr) * K + k0 + sc);
#pragma unroll
      for (int j = 0; j < 4; ++j) {
        float4 v = ga[j];
        As[sr * 32 + sc + j * 4 + 0] = (__bf16)v.x;
        As[sr * 32 + sc + j * 4 + 1] = (__bf16)v.y;
        As[sr * 32 + sc + j * 4 + 2] = (__bf16)v.z;
        As[sr * 32 + sc + j * 4 + 3] = (__bf16)v.w;
      }
    } else {
      const __bf16* Ab = (const __bf16*)Ap + (long)(bm + sr) * K + k0 + sc;
      *(bfrag*)(As + sr * 32 + sc) = *(const bfrag*)Ab;
      *(bfrag*)(As + sr * 32 + sc + 8) = *(const bfrag*)(Ab + 8);
    }
    {
      const float4* gb = (const float4*)(Bp + (long)(bn + sr) * K + k0 + sc);
#pragma unroll
      for (int j = 0; j < 4; ++j) {
        float4 v = gb[j];
        Bs[sr * 32 + sc + j * 4 + 0] = (__bf16)v.x;
        Bs[sr * 32 + sc + j * 4 + 1] = (__bf16)v.y;
        Bs[sr * 32 + sc + j * 4 + 2] = (__bf16)v.z;
        Bs[sr * 32 + sc + j * 4 + 3] = (__bf16)v.w;
      }
    }
    __syncthreads();
    bfrag af[4], bg[4];
#pragma unroll
    for (int mi = 0; mi < 4; ++mi)
      af[mi] = *(const bfrag*)(As + (wr + mi * 16 + lm) * 32 + quad * 8);
#pragma unroll
    for (int ni = 0; ni < 4; ++ni)
      bg[ni] = *(const bfrag*)(Bs + (wc + ni * 16 + lm) * 32 + quad * 8);
#pragma unroll
    for (int mi = 0; mi < 4; ++mi)
#pragma unroll
      for (int ni = 0; ni < 4; ++ni)
        acc[mi][ni] = __builtin_amdgcn_mfma_f32_16x16x32_bf16(af[mi], bg[ni], acc[mi][ni], 0, 0, 0);
    __syncthreads();
  }
#pragma unroll
  for (int mi = 0; mi < 4; ++mi)
#pragma unroll
    for (int ni = 0; ni < 4; ++ni)
#pragma unroll
      for (int r = 0; r < 4; ++r) {
        long row = bm + wr + mi * 16 + quad * 4 + r;
        long col = bn + wc + ni * 16 + lm;
        if (OUT_F32) ((float*)Cp)[row * N + col] = acc[mi][ni][r] * scl;
        else ((__bf16*)Cp)[row * N + col] = (__bf16)(acc[mi][ni][r] * scl);
      }
}

// ---------- flash attention v6: 4 q-tiles per block ----------
#define KP 72

template <bool DIAG>
__device__ __forceinline__ void attn_tile(
    const bfrag* qf, int row0, int kBase,
    const bfrag* kf, const bfrag* vf, __bf16* Psw,
    int lm, int quad, f4* yacc, f4& Lacc, bfrag ones) {
  f4 sac[4];
#pragma unroll
  for (int sub = 0; sub < 4; ++sub) {
    f4 z = {};
#pragma unroll
    for (int f = 0; f < 2; ++f)
      z = __builtin_amdgcn_mfma_f32_16x16x32_bf16(qf[f], kf[sub * 2 + f], z, 0, 0, 0);
    sac[sub] = z;
  }
  // P in kappa' order: kp(sub,lm) = lm*4+sub -> one b64 store per r
#pragma unroll
  for (int r = 0; r < 4; ++r) {
    bh4 pk;
#pragma unroll
    for (int sub = 0; sub < 4; ++sub) {
      float pv = __builtin_amdgcn_exp2f(sac[sub][r]);
      if (DIAG) {
        bool masked = (kBase + sub * 16 + lm > row0 + quad * 4 + r);
        pv = masked ? 0.f : pv;
      }
      pk[sub] = (__bf16)pv;
    }
    *(bh4*)(Psw + (quad * 4 + r) * KP + lm * 4) = pk;
  }
  __asm__ volatile("s_waitcnt lgkmcnt(0)" ::: "memory");  // wave-private P fence
#pragma unroll
  for (int f = 0; f < 2; ++f) {
    bfrag pf = *(const bfrag*)(Psw + lm * KP + f * 32 + quad * 8);
    Lacc = __builtin_amdgcn_mfma_f32_16x16x32_bf16(pf, ones, Lacc, 0, 0, 0);
#pragma unroll
    for (int ds = 0; ds < 4; ++ds)
      yacc[ds] = __builtin_amdgcn_mfma_f32_16x16x32_bf16(pf, vf[ds * 2 + f], yacc[ds], 0, 0, 0);
  }
}

// Block i in 0..7 handles q-tiles {i, 15-i, 16+i, 31-i} (66 tile-calls each).
// K/V staged+frag-loaded once per k-iter, shared by all active tiles.
template <bool VT>
__global__ __launch_bounds__(256, 2) void attn_fwd6(
    const __bf16* Qg, const __bf16* __restrict__ Kg,
    const __bf16* __restrict__ Vsrc, __bf16* Yg) {
  const int TT = 2048, CC = 1024;
  __shared__ __bf16 Ks[64 * KP];
  __shared__ __bf16 Vs[64 * KP];   // V^T in kappa' order: [d][kp]
  __shared__ __bf16 Ps[4 * 16 * KP];
  const int tid = threadIdx.x;
  const int wave = tid >> 6, lane = tid & 63;
  const int lm = lane & 15, quad = lane >> 4;
  const int i = blockIdx.x;                       // 0..7
  const int qtv[4] = {i, 15 - i, 16 + i, 31 - i}; // ascending extent
  const int b = blockIdx.y >> 4, h = blockIdx.y & 15;
  const long rbase = (long)b * TT;
  const int hoff = h * 64;
  int row0[4];
  bfrag qf[4][2];
#pragma unroll
  for (int t = 0; t < 4; ++t) {
    row0[t] = qtv[t] * 64 + wave * 16;
#pragma unroll
    for (int f = 0; f < 2; ++f)
      qf[t][f] = *(const bfrag*)(Qg + (rbase + row0[t] + lm) * CC + hoff + f * 32 + quad * 8);
  }
  bfrag ones;
#pragma unroll
  for (int j = 0; j < 8; ++j) ones[j] = (__bf16)1.0f;
  f4 y[4][4] = {};
  f4 L[4] = {};
  __bf16* Psw = Ps + wave * 16 * KP;
  const int ktMax = qtv[3];
  for (int kt = 0; kt <= ktMax; ++kt) {
    const int kBase = kt * 64;
    __syncthreads();
#pragma unroll
    for (int s = 0; s < 2; ++s) {   // K staging
      int idx = tid + s * 256;
      int r = idx >> 3, c = (idx & 7) * 8;
      *(bfrag*)(Ks + r * KP + c) =
          *(const bfrag*)(Kg + (rbase + kBase + r) * CC + hoff + c);
    }
    if (VT) {
#pragma unroll
      for (int s = 0; s < 2; ++s) { // V^T staging: straight b128 (already kappa')
        int idx = tid + s * 256;
        int d = idx >> 3, kc = (idx & 7) * 8;
        *(bfrag*)(Vs + d * KP + kc) =
            *(const bfrag*)(Vsrc + ((long)b * 1024 + hoff + d) * 2048 + kBase + kc);
      }
    } else {
#pragma unroll
      for (int s = 0; s < 2; ++s) { // fallback: scatter transpose into kappa' slots
        int idx = tid + s * 256;
        int r = idx >> 3, c = (idx & 7) * 8;
        int kp = (r & 15) * 4 + (r >> 4);
        bfrag vv = *(const bfrag*)(Vsrc + (rbase + kBase + r) * CC + hoff + c);
#pragma unroll
        for (int j = 0; j < 8; ++j) Vs[(c + j) * KP + kp] = vv[j];
      }
    }
    __syncthreads();
    bfrag kf[8], vf[8];
#pragma unroll
    for (int sub = 0; sub < 4; ++sub)
#pragma unroll
      for (int f = 0; f < 2; ++f) {
        kf[sub * 2 + f] = *(const bfrag*)(Ks + (sub * 16 + lm) * KP + f * 32 + quad * 8);
        vf[sub * 2 + f] = *(const bfrag*)(Vs + (sub * 16 + lm) * KP + f * 32 + quad * 8);
      }
#pragma unroll
    for (int t = 3; t >= 0; --t) {
      if (kt < qtv[t])
        attn_tile<false>(qf[t], row0[t], kBase, kf, vf, Psw, lm, quad, y[t], L[t], ones);
      else if (kt == qtv[t])
        attn_tile<true>(qf[t], row0[t], kBase, kf, vf, Psw, lm, quad, y[t], L[t], ones);
    }
  }
#pragma unroll
  for (int t = 0; t < 4; ++t)
#pragma unroll
    for (int ds = 0; ds < 4; ++ds)
#pragma unroll
      for (int r = 0; r < 4; ++r) {
        long row = rbase + row0[t] + quad * 4 + r;
        Yg[row * CC + hoff + ds * 16 + lm] = (__bf16)(y[t][ds][r] / L[t][r]);
      }
}

extern "C" void kernel_launch(void* const* d_in, const int* in_sizes, int n_in,
                              void* d_out, int out_size, void* d_ws, size_t ws_size,
                              hipStream_t stream) {
  (void)in_sizes; (void)n_in; (void)out_size;
  const float* x  = (const float*)d_in[0];
  const float* Wq = (const float*)d_in[1];
  const float* Wk = (const float*)d_in[2];
  const float* Wv = (const float*)d_in[3];
  const float* Wp = (const float*)d_in[4];
  float* out = (float*)d_out;
  const long R = 8192;             // B*T
  const long BUF = R * 1024;
  const long WN = 1024L * 1024;
  __bf16* qb = (__bf16*)d_ws;      // q (pre-scaled), then y in-place
  __bf16* kb = (__bf16*)d_out;     // k + vt borrow d_out (dead before final GEMM)
  __bf16* vslot = kb + BUF;        // vt (main) or v row-major (fallback)
  dim3 blk(256, 1, 1);
  const size_t need = (size_t)(2 * BUF + 4 * WN) * 2;
  if (ws_size >= need) {
    __bf16* xb = qb + BUF;
    __bf16* wqkv = xb + BUF;       // Wq,Wk,Wv contiguous = [3072][1024]
    __bf16* wpb = wqkv + 3 * WN;
    cvt5<<<dim3((unsigned)(BUF / (256 * 8)), 5, 1), blk, 0, stream>>>(
        x, Wq, Wk, Wv, Wp, xb, wqkv, wqkv + WN, wqkv + 2 * WN, wpb, BUF, WN);
    gemm_qkv<<<dim3(64, 24, 1), blk, 0, stream>>>(xb, wqkv, qb, kb, vslot, 8192, 1024);
    attn_fwd6<true><<<dim3(8, 64, 1), blk, 0, stream>>>(qb, kb, vslot, qb);
    gemm_bt_bf16<true><<<dim3(64, 8, 1), blk, 0, stream>>>(qb, wpb, out, 8192, 1024, 1024);
  } else {
    gemm_bt_cv<true, false><<<dim3(64, 8, 1), blk, 0, stream>>>(x, Wq, qb, 8192, 1024, 1024, QSCALE);
    gemm_bt_cv<true, false><<<dim3(64, 8, 1), blk, 0, stream>>>(x, Wk, kb, 8192, 1024, 1024, 1.0f);
    gemm_bt_cv<true, false><<<dim3(64, 8, 1), blk, 0, stream>>>(x, Wv, vslot, 8192, 1024, 1024, 1.0f);
    attn_fwd6<false><<<dim3(8, 64, 1), blk, 0, stream>>>(qb, kb, vslot, qb);
    gemm_bt_cv<false, true><<<dim3(64, 8, 1), blk, 0, stream>>>(qb, Wp, out, 8192, 1024, 1024, 1.0f);
  }
}

// Round 9
// 266.797 us; speedup vs baseline: 1.0918x; 1.0918x over previous
//
#include <hip/hip_runtime.h>

typedef __bf16 bfrag __attribute__((ext_vector_type(8)));
typedef __bf16 bh4 __attribute__((ext_vector_type(4)));
typedef float f4 __attribute__((ext_vector_type(4)));

#define AS1C(p) (const __attribute__((address_space(1))) void*)(p)
#define AS3(p)  (__attribute__((address_space(3))) void*)(p)

// 0.125 (=1/sqrt(64)) * log2(e): folded into Q so softmax is a bare exp2
#define QSCALE 0.18033688011112042f

__device__ __forceinline__ void g2l16(const __bf16* g, __bf16* l) {
  __builtin_amdgcn_global_load_lds(AS1C(g), AS3(l), 16, 0, 0);
}

// ---------- f32 -> bf16 bulk convert: x + 4 weights in one dispatch ----------
__global__ __launch_bounds__(256) void cvt5(
    const float* __restrict__ s0, const float* __restrict__ s1,
    const float* __restrict__ s2, const float* __restrict__ s3,
    const float* __restrict__ s4,
    __bf16* __restrict__ d0, __bf16* __restrict__ d1, __bf16* __restrict__ d2,
    __bf16* __restrict__ d3, __bf16* __restrict__ d4, long n0, long n1) {
  const float* s; __bf16* d; long n;
  switch (blockIdx.y) {
    case 0: s = s0; d = d0; n = n0; break;
    case 1: s = s1; d = d1; n = n1; break;
    case 2: s = s2; d = d2; n = n1; break;
    case 3: s = s3; d = d3; n = n1; break;
    default: s = s4; d = d4; n = n1; break;
  }
  long i = ((long)blockIdx.x * 256 + threadIdx.x) * 8;
  if (i >= n) return;
  float4 a = *(const float4*)(s + i);
  float4 b = *(const float4*)(s + i + 4);
  bfrag o;
  o[0] = (__bf16)a.x; o[1] = (__bf16)a.y; o[2] = (__bf16)a.z; o[3] = (__bf16)a.w;
  o[4] = (__bf16)b.x; o[5] = (__bf16)b.y; o[6] = (__bf16)b.z; o[7] = (__bf16)b.w;
  *(bfrag*)(d + i) = o;
}

// ---------- fused QKV GEMM, BK=64 (two BK-32 substages per barrier) ----------
__global__ __launch_bounds__(256) void gemm_qkv(
    const __bf16* __restrict__ A, const __bf16* __restrict__ B,
    __bf16* __restrict__ qb, __bf16* __restrict__ kb, __bf16* __restrict__ vt,
    int M, int K) {
  __shared__ __bf16 sbuf[16640];  // k-loop: As0|As1|Bs0|Bs1; V-epi: 128x130
  __bf16* As0 = sbuf;
  __bf16* As1 = sbuf + 4096;
  __bf16* Bs0 = sbuf + 8192;
  __bf16* Bs1 = sbuf + 12288;
  const int tid = threadIdx.x;
  const int wave = tid >> 6, lane = tid & 63;
  const int lm = lane & 15, quad = lane >> 4;
  const int bm = blockIdx.x * 128, bn = blockIdx.y * 128;
  const int wr = (wave >> 1) * 64, wc = (wave & 1) * 64;
  f4 acc[4][4] = {};
  for (int k0 = 0; k0 < K; k0 += 64) {
#pragma unroll
    for (int ii = 0; ii < 2; ++ii) {
      int s = ii * 4 + wave;
      int e = s * 512 + lane * 8;
      int r = e >> 5, c = e & 31;
      const __bf16* ar = A + (long)(bm + r) * K + k0 + c;
      const __bf16* br = B + (long)(bn + r) * K + k0 + c;
      g2l16(ar, As0 + e);
      g2l16(ar + 32, As1 + e);
      g2l16(br, Bs0 + e);
      g2l16(br + 32, Bs1 + e);
    }
    __syncthreads();
#pragma unroll
    for (int st = 0; st < 2; ++st) {
      const __bf16* As = st ? As1 : As0;
      const __bf16* Bs = st ? Bs1 : Bs0;
      bfrag af[4], bg[4];
#pragma unroll
      for (int mi = 0; mi < 4; ++mi)
        af[mi] = *(const bfrag*)(As + (wr + mi * 16 + lm) * 32 + quad * 8);
#pragma unroll
      for (int ni = 0; ni < 4; ++ni)
        bg[ni] = *(const bfrag*)(Bs + (wc + ni * 16 + lm) * 32 + quad * 8);
#pragma unroll
      for (int mi = 0; mi < 4; ++mi)
#pragma unroll
        for (int ni = 0; ni < 4; ++ni)
          acc[mi][ni] = __builtin_amdgcn_mfma_f32_16x16x32_bf16(af[mi], bg[ni], acc[mi][ni], 0, 0, 0);
    }
    __syncthreads();
  }
  if (bn < 2048) {
    __bf16* dst = (bn < 1024) ? qb : kb;
    const float scl = (bn < 1024) ? QSCALE : 1.0f;
    const int nb = bn & 1023;
#pragma unroll
    for (int mi = 0; mi < 4; ++mi)
#pragma unroll
      for (int ni = 0; ni < 4; ++ni)
#pragma unroll
        for (int r = 0; r < 4; ++r) {
          long row = bm + wr + mi * 16 + quad * 4 + r;
          long col = nb + wc + ni * 16 + lm;
          dst[row * 1024 + col] = (__bf16)(acc[mi][ni][r] * scl);
        }
  } else {
    // V: acc(row=t, col=d) -> vt[d][t'], t' = (t>>6)*64 + kappa'(t&63)
#pragma unroll
    for (int mi = 0; mi < 4; ++mi)
#pragma unroll
      for (int ni = 0; ni < 4; ++ni)
#pragma unroll
        for (int r = 0; r < 4; ++r) {
          int d = wc + ni * 16 + lm;
          int tp = (wr ? 64 : 0) + (quad * 4 + r) * 4 + mi;
          sbuf[d * 130 + tp] = (__bf16)acc[mi][ni][r];
        }
    __syncthreads();
    const int bloc = bm >> 11;
    const int tloc = bm & 2047;
#pragma unroll
    for (int p = 0; p < 8; ++p) {
      int d = (tid >> 4) + p * 16;
      int c = (tid & 15) * 8;
      long dglob = (bn - 2048) + d;
      *(bfrag*)(vt + ((long)bloc * 1024 + dglob) * 2048 + tloc + c) =
          *(const bfrag*)(sbuf + d * 130 + c);
    }
  }
}

// ---------- plain GEMM (bf16 in), BK=64, final projection ----------
template <bool OUT_F32>
__global__ __launch_bounds__(256) void gemm_bt_bf16(
    const __bf16* __restrict__ A, const __bf16* __restrict__ B,
    void* __restrict__ Cp, int M, int N, int K) {
  __shared__ __bf16 sbuf[16384];
  __bf16* As0 = sbuf;
  __bf16* As1 = sbuf + 4096;
  __bf16* Bs0 = sbuf + 8192;
  __bf16* Bs1 = sbuf + 12288;
  const int tid = threadIdx.x;
  const int wave = tid >> 6, lane = tid & 63;
  const int lm = lane & 15, quad = lane >> 4;
  const int bm = blockIdx.x * 128, bn = blockIdx.y * 128;
  const int wr = (wave >> 1) * 64, wc = (wave & 1) * 64;
  f4 acc[4][4] = {};
  for (int k0 = 0; k0 < K; k0 += 64) {
#pragma unroll
    for (int ii = 0; ii < 2; ++ii) {
      int s = ii * 4 + wave;
      int e = s * 512 + lane * 8;
      int r = e >> 5, c = e & 31;
      const __bf16* ar = A + (long)(bm + r) * K + k0 + c;
      const __bf16* br = B + (long)(bn + r) * K + k0 + c;
      g2l16(ar, As0 + e);
      g2l16(ar + 32, As1 + e);
      g2l16(br, Bs0 + e);
      g2l16(br + 32, Bs1 + e);
    }
    __syncthreads();
#pragma unroll
    for (int st = 0; st < 2; ++st) {
      const __bf16* As = st ? As1 : As0;
      const __bf16* Bs = st ? Bs1 : Bs0;
      bfrag af[4], bg[4];
#pragma unroll
      for (int mi = 0; mi < 4; ++mi)
        af[mi] = *(const bfrag*)(As + (wr + mi * 16 + lm) * 32 + quad * 8);
#pragma unroll
      for (int ni = 0; ni < 4; ++ni)
        bg[ni] = *(const bfrag*)(Bs + (wc + ni * 16 + lm) * 32 + quad * 8);
#pragma unroll
      for (int mi = 0; mi < 4; ++mi)
#pragma unroll
        for (int ni = 0; ni < 4; ++ni)
          acc[mi][ni] = __builtin_amdgcn_mfma_f32_16x16x32_bf16(af[mi], bg[ni], acc[mi][ni], 0, 0, 0);
    }
    __syncthreads();
  }
#pragma unroll
  for (int mi = 0; mi < 4; ++mi)
#pragma unroll
    for (int ni = 0; ni < 4; ++ni)
#pragma unroll
      for (int r = 0; r < 4; ++r) {
        long row = bm + wr + mi * 16 + quad * 4 + r;
        long col = bn + wc + ni * 16 + lm;
        if (OUT_F32) ((float*)Cp)[row * N + col] = acc[mi][ni][r];
        else ((__bf16*)Cp)[row * N + col] = (__bf16)acc[mi][ni][r];
      }
}

// ---------- fallback GEMM (f32 A / f32 B, inline convert) ----------
template <bool A_F32, bool OUT_F32>
__global__ __launch_bounds__(256) void gemm_bt_cv(
    const void* __restrict__ Ap, const float* __restrict__ Bp,
    void* __restrict__ Cp, int M, int N, int K, float scl) {
  __shared__ __bf16 As[128 * 32];
  __shared__ __bf16 Bs[128 * 32];
  const int tid = threadIdx.x;
  const int lane = tid & 63, wave = tid >> 6;
  const int lm = lane & 15, quad = lane >> 4;
  const int bm = blockIdx.x * 128, bn = blockIdx.y * 128;
  const int wr = (wave >> 1) * 64, wc = (wave & 1) * 64;
  const int e0 = tid * 16, sr = e0 >> 5, sc = e0 & 31;
  f4 acc[4][4] = {};
  for (int k0 = 0; k0 < K; k0 += 32) {
    if (A_F32) {
      const float4* ga = (const float4*)((const float*)Ap + (long)(bm + sr) * K + k0 + sc);
#pragma unroll
      for (int j = 0; j < 4; ++j) {
        float4 v = ga[j];
        As[sr * 32 + sc + j * 4 + 0] = (__bf16)v.x;
        As[sr * 32 + sc + j * 4 + 1] = (__bf16)v.y;
        As[sr * 32 + sc + j * 4 + 2] = (__bf16)v.z;
        As[sr * 32 + sc + j * 4 + 3] = (__bf16)v.w;
      }
    } else {
      const __bf16* Ab = (const __bf16*)Ap + (long)(bm + sr) * K + k0 + sc;
      *(bfrag*)(As + sr * 32 + sc) = *(const bfrag*)Ab;
      *(bfrag*)(As + sr * 32 + sc + 8) = *(const bfrag*)(Ab + 8);
    }
    {
      const float4* gb = (const float4*)(Bp + (long)(bn + sr) * K + k0 + sc);
#pragma unroll
      for (int j = 0; j < 4; ++j) {
        float4 v = gb[j];
        Bs[sr * 32 + sc + j * 4 + 0] = (__bf16)v.x;
        Bs[sr * 32 + sc + j * 4 + 1] = (__bf16)v.y;
        Bs[sr * 32 + sc + j * 4 + 2] = (__bf16)v.z;
        Bs[sr * 32 + sc + j * 4 + 3] = (__bf16)v.w;
      }
    }
    __syncthreads();
    bfrag af[4], bg[4];
#pragma unroll
    for (int mi = 0; mi < 4; ++mi)
      af[mi] = *(const bfrag*)(As + (wr + mi * 16 + lm) * 32 + quad * 8);
#pragma unroll
    for (int ni = 0; ni < 4; ++ni)
      bg[ni] = *(const bfrag*)(Bs + (wc + ni * 16 + lm) * 32 + quad * 8);
#pragma unroll
    for (int mi = 0; mi < 4; ++mi)
#pragma unroll
      for (int ni = 0; ni < 4; ++ni)
        acc[mi][ni] = __builtin_amdgcn_mfma_f32_16x16x32_bf16(af[mi], bg[ni], acc[mi][ni], 0, 0, 0);
    __syncthreads();
  }
#pragma unroll
  for (int mi = 0; mi < 4; ++mi)
#pragma unroll
    for (int ni = 0; ni < 4; ++ni)
#pragma unroll
      for (int r = 0; r < 4; ++r) {
        long row = bm + wr + mi * 16 + quad * 4 + r;
        long col = bn + wc + ni * 16 + lm;
        if (OUT_F32) ((float*)Cp)[row * N + col] = acc[mi][ni][r] * scl;
        else ((__bf16*)Cp)[row * N + col] = (__bf16)(acc[mi][ni][r] * scl);
      }
}

// ---------- flash attention v7: 2 q-tiles, fused interleaved body ----------
#define KP 72

// single-tile path (used when only tile B is still active)
template <bool DIAG>
__device__ __forceinline__ void attn_tile(
    const bfrag* qf, int row0, int kBase,
    const bfrag* kf, const bfrag* vf, __bf16* Psw,
    int lm, int quad, f4* yacc, f4& Lacc, bfrag ones) {
  f4 sac[4];
#pragma unroll
  for (int sub = 0; sub < 4; ++sub) {
    f4 z = {};
#pragma unroll
    for (int f = 0; f < 2; ++f)
      z = __builtin_amdgcn_mfma_f32_16x16x32_bf16(qf[f], kf[sub * 2 + f], z, 0, 0, 0);
    sac[sub] = z;
  }
#pragma unroll
  for (int r = 0; r < 4; ++r) {
    bh4 pk;
#pragma unroll
    for (int sub = 0; sub < 4; ++sub) {
      float pv = __builtin_amdgcn_exp2f(sac[sub][r]);
      if (DIAG) {
        bool masked = (kBase + sub * 16 + lm > row0 + quad * 4 + r);
        pv = masked ? 0.f : pv;
      }
      pk[sub] = (__bf16)pv;
    }
    *(bh4*)(Psw + (quad * 4 + r) * KP + lm * 4) = pk;
  }
  __asm__ volatile("s_waitcnt lgkmcnt(0)" ::: "memory");
#pragma unroll
  for (int f = 0; f < 2; ++f) {
    bfrag pf = *(const bfrag*)(Psw + lm * KP + f * 32 + quad * 8);
    Lacc = __builtin_amdgcn_mfma_f32_16x16x32_bf16(pf, ones, Lacc, 0, 0, 0);
#pragma unroll
    for (int ds = 0; ds < 4; ++ds)
      yacc[ds] = __builtin_amdgcn_mfma_f32_16x16x32_bf16(pf, vf[ds * 2 + f], yacc[ds], 0, 0, 0);
  }
}

// dual-tile path: interleaved independent chains, ONE fence per k-iter.
// kt <= qtA < qtB so tile B is never diagonal here.
template <bool DIAG_A>
__device__ __forceinline__ void attn_tile2(
    const bfrag* qfA, const bfrag* qfB, int rowA0, int kBase,
    const bfrag* kf, const bfrag* vf, __bf16* PswA, __bf16* PswB,
    int lm, int quad, f4* yA, f4* yB, f4& LA, f4& LB, bfrag ones) {
  f4 sA[4], sB[4];
#pragma unroll
  for (int sub = 0; sub < 4; ++sub) {
    f4 za = {}, zb = {};
#pragma unroll
    for (int f = 0; f < 2; ++f) {
      za = __builtin_amdgcn_mfma_f32_16x16x32_bf16(qfA[f], kf[sub * 2 + f], za, 0, 0, 0);
      zb = __builtin_amdgcn_mfma_f32_16x16x32_bf16(qfB[f], kf[sub * 2 + f], zb, 0, 0, 0);
    }
    sA[sub] = za; sB[sub] = zb;
  }
#pragma unroll
  for (int r = 0; r < 4; ++r) {
    bh4 pa, pb;
#pragma unroll
    for (int sub = 0; sub < 4; ++sub) {
      float va = __builtin_amdgcn_exp2f(sA[sub][r]);
      if (DIAG_A) {
        bool masked = (kBase + sub * 16 + lm > rowA0 + quad * 4 + r);
        va = masked ? 0.f : va;
      }
      pa[sub] = (__bf16)va;
      pb[sub] = (__bf16)__builtin_amdgcn_exp2f(sB[sub][r]);
    }
    *(bh4*)(PswA + (quad * 4 + r) * KP + lm * 4) = pa;
    *(bh4*)(PswB + (quad * 4 + r) * KP + lm * 4) = pb;
  }
  __asm__ volatile("s_waitcnt lgkmcnt(0)" ::: "memory");  // single fence
#pragma unroll
  for (int f = 0; f < 2; ++f) {
    bfrag pfa = *(const bfrag*)(PswA + lm * KP + f * 32 + quad * 8);
    bfrag pfb = *(const bfrag*)(PswB + lm * KP + f * 32 + quad * 8);
    LA = __builtin_amdgcn_mfma_f32_16x16x32_bf16(pfa, ones, LA, 0, 0, 0);
    LB = __builtin_amdgcn_mfma_f32_16x16x32_bf16(pfb, ones, LB, 0, 0, 0);
#pragma unroll
    for (int ds = 0; ds < 4; ++ds) {
      yA[ds] = __builtin_amdgcn_mfma_f32_16x16x32_bf16(pfa, vf[ds * 2 + f], yA[ds], 0, 0, 0);
      yB[ds] = __builtin_amdgcn_mfma_f32_16x16x32_bf16(pfb, vf[ds * 2 + f], yB[ds], 0, 0, 0);
    }
  }
}

// Block i handles q-tiles {i, 31-i}. VT: Vsrc pre-transposed + kappa'.
template <bool VT>
__global__ __launch_bounds__(256) void attn_fwd7(
    const __bf16* Qg, const __bf16* __restrict__ Kg,
    const __bf16* __restrict__ Vsrc, __bf16* Yg) {
  const int TT = 2048, CC = 1024;
  __shared__ __bf16 Ks[64 * KP];
  __shared__ __bf16 Vs[64 * KP];       // V^T kappa': [d][kp]
  __shared__ __bf16 Ps[8 * 16 * KP];   // two P regions per wave
  const int tid = threadIdx.x;
  const int wave = tid >> 6, lane = tid & 63;
  const int lm = lane & 15, quad = lane >> 4;
  const int i = blockIdx.x;
  const int qtA = i, qtB = 31 - i;
  const int b = blockIdx.y >> 4, h = blockIdx.y & 15;
  const long rbase = (long)b * TT;
  const int hoff = h * 64;
  const int rowA0 = qtA * 64 + wave * 16, rowB0 = qtB * 64 + wave * 16;
  bfrag qfA[2], qfB[2];
#pragma unroll
  for (int f = 0; f < 2; ++f) {
    qfA[f] = *(const bfrag*)(Qg + (rbase + rowA0 + lm) * CC + hoff + f * 32 + quad * 8);
    qfB[f] = *(const bfrag*)(Qg + (rbase + rowB0 + lm) * CC + hoff + f * 32 + quad * 8);
  }
  bfrag ones;
#pragma unroll
  for (int j = 0; j < 8; ++j) ones[j] = (__bf16)1.0f;
  f4 yA[4] = {}, yB[4] = {};
  f4 LA = {}, LB = {};
  __bf16* PswA = Ps + wave * 16 * KP;
  __bf16* PswB = Ps + (wave + 4) * 16 * KP;
  for (int kt = 0; kt <= qtB; ++kt) {
    const int kBase = kt * 64;
    __syncthreads();
#pragma unroll
    for (int s = 0; s < 2; ++s) {   // K staging
      int idx = tid + s * 256;
      int r = idx >> 3, c = (idx & 7) * 8;
      *(bfrag*)(Ks + r * KP + c) =
          *(const bfrag*)(Kg + (rbase + kBase + r) * CC + hoff + c);
    }
    if (VT) {
#pragma unroll
      for (int s = 0; s < 2; ++s) { // V^T staging: straight b128
        int idx = tid + s * 256;
        int d = idx >> 3, kc = (idx & 7) * 8;
        *(bfrag*)(Vs + d * KP + kc) =
            *(const bfrag*)(Vsrc + ((long)b * 1024 + hoff + d) * 2048 + kBase + kc);
      }
    } else {
#pragma unroll
      for (int s = 0; s < 2; ++s) { // fallback: scatter transpose into kappa'
        int idx = tid + s * 256;
        int r = idx >> 3, c = (idx & 7) * 8;
        int kp = (r & 15) * 4 + (r >> 4);
        bfrag vv = *(const bfrag*)(Vsrc + (rbase + kBase + r) * CC + hoff + c);
#pragma unroll
        for (int j = 0; j < 8; ++j) Vs[(c + j) * KP + kp] = vv[j];
      }
    }
    __syncthreads();
    bfrag kf[8], vf[8];
#pragma unroll
    for (int sub = 0; sub < 4; ++sub)
#pragma unroll
      for (int f = 0; f < 2; ++f) {
        kf[sub * 2 + f] = *(const bfrag*)(Ks + (sub * 16 + lm) * KP + f * 32 + quad * 8);
        vf[sub * 2 + f] = *(const bfrag*)(Vs + (sub * 16 + lm) * KP + f * 32 + quad * 8);
      }
    if (kt < qtA)
      attn_tile2<false>(qfA, qfB, rowA0, kBase, kf, vf, PswA, PswB, lm, quad, yA, yB, LA, LB, ones);
    else if (kt == qtA)
      attn_tile2<true>(qfA, qfB, rowA0, kBase, kf, vf, PswA, PswB, lm, quad, yA, yB, LA, LB, ones);
    else if (kt < qtB)
      attn_tile<false>(qfB, rowB0, kBase, kf, vf, PswB, lm, quad, yB, LB, ones);
    else
      attn_tile<true>(qfB, rowB0, kBase, kf, vf, PswB, lm, quad, yB, LB, ones);
  }
#pragma unroll
  for (int ds = 0; ds < 4; ++ds)
#pragma unroll
    for (int r = 0; r < 4; ++r) {
      long rowa = rbase + rowA0 + quad * 4 + r;
      long rowb = rbase + rowB0 + quad * 4 + r;
      Yg[rowa * CC + hoff + ds * 16 + lm] = (__bf16)(yA[ds][r] / LA[r]);
      Yg[rowb * CC + hoff + ds * 16 + lm] = (__bf16)(yB[ds][r] / LB[r]);
    }
}

extern "C" void kernel_launch(void* const* d_in, const int* in_sizes, int n_in,
                              void* d_out, int out_size, void* d_ws, size_t ws_size,
                              hipStream_t stream) {
  (void)in_sizes; (void)n_in; (void)out_size;
  const float* x  = (const float*)d_in[0];
  const float* Wq = (const float*)d_in[1];
  const float* Wk = (const float*)d_in[2];
  const float* Wv = (const float*)d_in[3];
  const float* Wp = (const float*)d_in[4];
  float* out = (float*)d_out;
  const long R = 8192;             // B*T
  const long BUF = R * 1024;
  const long WN = 1024L * 1024;
  __bf16* qb = (__bf16*)d_ws;      // q (pre-scaled), then y in-place
  __bf16* kb = (__bf16*)d_out;     // k + vt borrow d_out (dead before final GEMM)
  __bf16* vslot = kb + BUF;
  dim3 blk(256, 1, 1);
  const size_t need = (size_t)(2 * BUF + 4 * WN) * 2;
  if (ws_size >= need) {
    __bf16* xb = qb + BUF;
    __bf16* wqkv = xb + BUF;       // Wq,Wk,Wv contiguous = [3072][1024]
    __bf16* wpb = wqkv + 3 * WN;
    cvt5<<<dim3((unsigned)(BUF / (256 * 8)), 5, 1), blk, 0, stream>>>(
        x, Wq, Wk, Wv, Wp, xb, wqkv, wqkv + WN, wqkv + 2 * WN, wpb, BUF, WN);
    gemm_qkv<<<dim3(64, 24, 1), blk, 0, stream>>>(xb, wqkv, qb, kb, vslot, 8192, 1024);
    attn_fwd7<true><<<dim3(16, 64, 1), blk, 0, stream>>>(qb, kb, vslot, qb);
    gemm_bt_bf16<true><<<dim3(64, 8, 1), blk, 0, stream>>>(qb, wpb, out, 8192, 1024, 1024);
  } else {
    gemm_bt_cv<true, false><<<dim3(64, 8, 1), blk, 0, stream>>>(x, Wq, qb, 8192, 1024, 1024, QSCALE);
    gemm_bt_cv<true, false><<<dim3(64, 8, 1), blk, 0, stream>>>(x, Wk, kb, 8192, 1024, 1024, 1.0f);
    gemm_bt_cv<true, false><<<dim3(64, 8, 1), blk, 0, stream>>>(x, Wv, vslot, 8192, 1024, 1024, 1.0f);
    attn_fwd7<false><<<dim3(16, 64, 1), blk, 0, stream>>>(qb, kb, vslot, qb);
    gemm_bt_cv<false, true><<<dim3(64, 8, 1), blk, 0, stream>>>(qb, Wp, out, 8192, 1024, 1024, 1.0f);
  }
}